// Round 2
// baseline (535.886 us; speedup 1.0000x reference)
//
#include <hip/hip_runtime.h>

// Problem: B=8, Lq=Lk=1024, D=1024, H=8, dh=128.
// out0: (B,Lq,D) fp32 ; out1: similarity (H*B, Lq, Lk) fp32 (concatenated in d_out).
// Pipeline: [qkv proj bf16] -> [V transpose] -> [logits+bias+mask -> sim] -> [row softmax in-place] -> [PV -> out]

#define TB 256
#define LDST 56  // LDS row stride (elems) for 32-wide bf16 tiles: 112B = 16B-aligned, ~2-way bank conflict (free)

typedef __attribute__((ext_vector_type(8))) short short8;
typedef __attribute__((ext_vector_type(4))) float f32x4;
typedef unsigned short u16;

__device__ __forceinline__ u16 f2bf(float f) {
  union { float f; unsigned u; } v; v.f = f;
  unsigned r = v.u + 0x7fffu + ((v.u >> 16) & 1u);  // round-to-nearest-even
  return (u16)(r >> 16);
}

// ---------------- Kernel 1: QKV projections  y = x @ W^T  (NT GEMM, fp32 in, bf16 out) ----------------
// z=0: Q=query@Wq^T ; z=1: K=keys@Wk^T ; z=2: V=keys@Wv^T.  Output layout (b,h,l,dh) bf16.
__global__ __launch_bounds__(TB) void qkv_gemm(
    const float* __restrict__ query, const float* __restrict__ keys,
    const float* __restrict__ Wq, const float* __restrict__ Wk, const float* __restrict__ Wv,
    u16* __restrict__ Qb, u16* __restrict__ Kb, u16* __restrict__ Vb) {
  __shared__ u16 As[128 * LDST];
  __shared__ u16 Bs[128 * LDST];
  const int z = blockIdx.z;
  const float* __restrict__ x = (z == 0) ? query : keys;
  const float* __restrict__ W = (z == 0) ? Wq : (z == 1) ? Wk : Wv;
  u16* __restrict__ dst = (z == 0) ? Qb : (z == 1) ? Kb : Vb;

  const int t = threadIdx.x;
  const int lane = t & 63, wid = t >> 6;
  const int wr = wid >> 1, wc = wid & 1;
  const int fr = lane & 15, ko = (lane >> 4) * 8;
  const int m0 = blockIdx.x * 128, n0 = blockIdx.y * 128;

  f32x4 acc[4][4] = {};

  for (int k0 = 0; k0 < 1024; k0 += 32) {
#pragma unroll
    for (int it = 0; it < 4; ++it) {  // stage 128x32 fp32 -> bf16 LDS, both tiles
      int j = it * 256 + t;
      int row = j >> 3, c4 = (j & 7) * 4;
      float4 va = *(const float4*)&x[(size_t)(m0 + row) * 1024 + k0 + c4];
      float4 vb = *(const float4*)&W[(size_t)(n0 + row) * 1024 + k0 + c4];
      *(ushort4*)&As[row * LDST + c4] = make_ushort4(f2bf(va.x), f2bf(va.y), f2bf(va.z), f2bf(va.w));
      *(ushort4*)&Bs[row * LDST + c4] = make_ushort4(f2bf(vb.x), f2bf(vb.y), f2bf(vb.z), f2bf(vb.w));
    }
    __syncthreads();
    short8 a[4], bfrag[4];
#pragma unroll
    for (int i = 0; i < 4; ++i) a[i] = *(const short8*)&As[(wr * 64 + i * 16 + fr) * LDST + ko];
#pragma unroll
    for (int j = 0; j < 4; ++j) bfrag[j] = *(const short8*)&Bs[(wc * 64 + j * 16 + fr) * LDST + ko];
#pragma unroll
    for (int i = 0; i < 4; ++i)
#pragma unroll
      for (int j = 0; j < 4; ++j)
        acc[i][j] = __builtin_amdgcn_mfma_f32_16x16x32_bf16(a[i], bfrag[j], acc[i][j], 0, 0, 0);
    __syncthreads();
  }

  const int h = blockIdx.y;  // N-tile == head since dh == 128
#pragma unroll
  for (int i = 0; i < 4; ++i)
#pragma unroll
    for (int j = 0; j < 4; ++j)
#pragma unroll
      for (int r = 0; r < 4; ++r) {
        int m = m0 + wr * 64 + i * 16 + (lane >> 4) * 4 + r;  // C row (verified m89 layout)
        int d = wc * 64 + j * 16 + fr;                        // C col
        int b_ = m >> 10, q = m & 1023;
        dst[(((size_t)(b_ * 8 + h)) * 1024 + q) * 128 + d] = f2bf(acc[i][j][r]);
      }
}

// ---------------- Kernel 2: V transpose  (b,h,k,d) -> (b,h,d,k) ----------------
__global__ __launch_bounds__(TB) void vtrans(const u16* __restrict__ Vb, u16* __restrict__ Vt) {
  __shared__ u16 tile[32][33];
  const int bh = blockIdx.z;
  const u16* __restrict__ src = Vb + (size_t)bh * 1024 * 128;
  u16* __restrict__ dst = Vt + (size_t)bh * 128 * 1024;
  const int k0 = blockIdx.x * 32, d0 = blockIdx.y * 32;
  const int t = threadIdx.x;
#pragma unroll
  for (int i = 0; i < 4; ++i) {
    int j = i * 256 + t;
    int r = j >> 5, c = j & 31;
    tile[r][c] = src[(size_t)(k0 + r) * 128 + d0 + c];
  }
  __syncthreads();
#pragma unroll
  for (int i = 0; i < 4; ++i) {
    int j = i * 256 + t;
    int r = j >> 5, c = j & 31;
    dst[(size_t)(d0 + r) * 1024 + k0 + c] = tile[c][r];
  }
}

// ---------------- Kernel 3: logits  S = (Q.K^T + rel)/32, masked -> sim (fp32) ----------------
__global__ __launch_bounds__(TB) void logits_kernel(
    const u16* __restrict__ Qb, const u16* __restrict__ Kb,
    const int* __restrict__ mask, const float* __restrict__ rel,
    float* __restrict__ sim) {
  __shared__ u16 As[128 * LDST];
  __shared__ u16 Bs[128 * LDST];
  const int z = blockIdx.z;
  const int h = z >> 3, b = z & 7;
  const u16* __restrict__ Aq = Qb + (size_t)(b * 8 + h) * 1024 * 128;
  const u16* __restrict__ Ak = Kb + (size_t)(b * 8 + h) * 1024 * 128;
  const int q0 = blockIdx.x * 128, p0 = blockIdx.y * 128;

  const int t = threadIdx.x;
  const int lane = t & 63, wid = t >> 6;
  const int wr = wid >> 1, wc = wid & 1;
  const int fr = lane & 15, ko = (lane >> 4) * 8;

  f32x4 acc[4][4] = {};

  for (int ks = 0; ks < 128; ks += 32) {
#pragma unroll
    for (int it = 0; it < 2; ++it) {  // stage 128x32 bf16 tiles (copy)
      int j = it * 256 + t;
      int row = j >> 2, c8 = (j & 3) * 8;
      *(short8*)&As[row * LDST + c8] = *(const short8*)&Aq[(size_t)(q0 + row) * 128 + ks + c8];
      *(short8*)&Bs[row * LDST + c8] = *(const short8*)&Ak[(size_t)(p0 + row) * 128 + ks + c8];
    }
    __syncthreads();
    short8 a[4], bfrag[4];
#pragma unroll
    for (int i = 0; i < 4; ++i) a[i] = *(const short8*)&As[(wr * 64 + i * 16 + fr) * LDST + ko];
#pragma unroll
    for (int j = 0; j < 4; ++j) bfrag[j] = *(const short8*)&Bs[(wc * 64 + j * 16 + fr) * LDST + ko];
#pragma unroll
    for (int i = 0; i < 4; ++i)
#pragma unroll
      for (int j = 0; j < 4; ++j)
        acc[i][j] = __builtin_amdgcn_mfma_f32_16x16x32_bf16(a[i], bfrag[j], acc[i][j], 0, 0, 0);
    __syncthreads();
  }

  const float scale = 0.03125f;  // 1/sqrt(1024)
#pragma unroll
  for (int i = 0; i < 4; ++i)
#pragma unroll
    for (int j = 0; j < 4; ++j)
#pragma unroll
      for (int r = 0; r < 4; ++r) {
        int q = q0 + wr * 64 + i * 16 + (lane >> 4) * 4 + r;
        int p = p0 + wc * 64 + j * 16 + fr;
        size_t mi = ((size_t)b * 1024 + q) * 1024 + p;
        // Reference: attn = (QK^T + rel) / sqrt(D), THEN mask.
        float logit = (acc[i][j][r] + rel[mi]) * scale;
        float val = (mask[mi] > 0) ? logit : -1e9f;
        sim[((size_t)(h * 8 + b) * 1024 + q) * 1024 + p] = val;
      }
}

// ---------------- Kernel 4: in-place row softmax over 1024-wide rows ----------------
__global__ __launch_bounds__(TB) void softmax_rows(float* __restrict__ sim) {
  const size_t row = blockIdx.x;
  float* __restrict__ p = sim + row * 1024;
  const int t = threadIdx.x;
  float4 v = ((float4*)p)[t];
  float m = fmaxf(fmaxf(v.x, v.y), fmaxf(v.z, v.w));
#pragma unroll
  for (int o = 32; o; o >>= 1) m = fmaxf(m, __shfl_xor(m, o));
  __shared__ float redm[4];
  __shared__ float reds[4];
  const int wid = t >> 6, lane = t & 63;
  if (lane == 0) redm[wid] = m;
  __syncthreads();
  m = fmaxf(fmaxf(redm[0], redm[1]), fmaxf(redm[2], redm[3]));
  float e0 = __expf(v.x - m), e1 = __expf(v.y - m), e2 = __expf(v.z - m), e3 = __expf(v.w - m);
  float s = e0 + e1 + e2 + e3;
#pragma unroll
  for (int o = 32; o; o >>= 1) s += __shfl_xor(s, o);
  if (lane == 0) reds[wid] = s;
  __syncthreads();
  s = reds[0] + reds[1] + reds[2] + reds[3];
  float inv = 1.0f / s;
  float4 o4;
  o4.x = e0 * inv; o4.y = e1 * inv; o4.z = e2 * inv; o4.w = e3 * inv;
  ((float4*)p)[t] = o4;
}

// ---------------- Kernel 5: out = P @ V  (P fp32 from sim -> bf16; Vt is (b,h,d,k)) ----------------
__global__ __launch_bounds__(TB) void pv_kernel(
    const float* __restrict__ sim, const u16* __restrict__ Vt, float* __restrict__ out) {
  __shared__ u16 As[128 * LDST];
  __shared__ u16 Bs[128 * LDST];
  const int z = blockIdx.y;
  const int h = z >> 3, b = z & 7;
  const float* __restrict__ P = sim + (size_t)(h * 8 + b) * 1024 * 1024;
  const u16* __restrict__ Vp = Vt + (size_t)(b * 8 + h) * 128 * 1024;
  const int q0 = blockIdx.x * 128;

  const int t = threadIdx.x;
  const int lane = t & 63, wid = t >> 6;
  const int wr = wid >> 1, wc = wid & 1;
  const int fr = lane & 15, ko = (lane >> 4) * 8;

  f32x4 acc[4][4] = {};

  for (int k0 = 0; k0 < 1024; k0 += 32) {
#pragma unroll
    for (int it = 0; it < 4; ++it) {  // A: P fp32 -> bf16
      int j = it * 256 + t;
      int row = j >> 3, c4 = (j & 7) * 4;
      float4 v = *(const float4*)&P[(size_t)(q0 + row) * 1024 + k0 + c4];
      *(ushort4*)&As[row * LDST + c4] = make_ushort4(f2bf(v.x), f2bf(v.y), f2bf(v.z), f2bf(v.w));
    }
#pragma unroll
    for (int it = 0; it < 2; ++it) {  // B: Vt rows are d (128), k-contiguous
      int j = it * 256 + t;
      int row = j >> 2, c8 = (j & 3) * 8;
      *(short8*)&Bs[row * LDST + c8] = *(const short8*)&Vp[(size_t)row * 1024 + k0 + c8];
    }
    __syncthreads();
    short8 a[4], bfrag[4];
#pragma unroll
    for (int i = 0; i < 4; ++i) a[i] = *(const short8*)&As[(wr * 64 + i * 16 + fr) * LDST + ko];
#pragma unroll
    for (int j = 0; j < 4; ++j) bfrag[j] = *(const short8*)&Bs[(wc * 64 + j * 16 + fr) * LDST + ko];
#pragma unroll
    for (int i = 0; i < 4; ++i)
#pragma unroll
      for (int j = 0; j < 4; ++j)
        acc[i][j] = __builtin_amdgcn_mfma_f32_16x16x32_bf16(a[i], bfrag[j], acc[i][j], 0, 0, 0);
    __syncthreads();
  }

#pragma unroll
  for (int i = 0; i < 4; ++i)
#pragma unroll
    for (int j = 0; j < 4; ++j)
#pragma unroll
      for (int r = 0; r < 4; ++r) {
        int q = q0 + wr * 64 + i * 16 + (lane >> 4) * 4 + r;
        int d = wc * 64 + j * 16 + fr;
        out[((size_t)b * 1024 + q) * 1024 + h * 128 + d] = acc[i][j][r];
      }
}

extern "C" void kernel_launch(void* const* d_in, const int* in_sizes, int n_in,
                              void* d_out, int out_size, void* d_ws, size_t ws_size,
                              hipStream_t stream) {
  (void)in_sizes; (void)n_in; (void)out_size; (void)ws_size;
  const float* query = (const float*)d_in[0];
  const float* keys  = (const float*)d_in[1];
  const int*   mask  = (const int*)d_in[2];
  const float* rel   = (const float*)d_in[3];
  const float* Wq    = (const float*)d_in[4];
  const float* Wk    = (const float*)d_in[5];
  const float* Wv    = (const float*)d_in[6];

  float* out = (float*)d_out;                       // (B,Lq,D) = 8M floats
  float* sim = out + (size_t)8 * 1024 * 1024;       // (H*B,Lq,Lk) = 64M floats

  const size_t NE = (size_t)8 * 8 * 1024 * 128;     // 8.39M bf16 elems per buffer
  u16* Qb = (u16*)d_ws;                             // ws usage: 64 MB total
  u16* Kb = Qb + NE;
  u16* Vb = Kb + NE;
  u16* Vt = Vb + NE;

  qkv_gemm<<<dim3(64, 8, 3), TB, 0, stream>>>(query, keys, Wq, Wk, Wv, Qb, Kb, Vb);
  vtrans<<<dim3(32, 4, 64), TB, 0, stream>>>(Vb, Vt);
  logits_kernel<<<dim3(8, 8, 64), TB, 0, stream>>>(Qb, Kb, mask, rel, sim);
  softmax_rows<<<dim3(64 * 1024), TB, 0, stream>>>(sim);
  pv_kernel<<<dim3(8, 64), TB, 0, stream>>>(sim, Vt, out);
}

// Round 3
// 355.345 us; speedup vs baseline: 1.5081x; 1.5081x over previous
//
#include <hip/hip_runtime.h>

// Problem: B=8, Lq=Lk=1024, D=1024, H=8, dh=128.
// out0: (B,Lq,D) fp32 ; out1: similarity (H*B, Lq, Lk) fp32 (concatenated in d_out).
// Pipeline: [qkv proj bf16] -> [V transpose] -> [fused logits+softmax+PV]

#define TB 256
#define LDST 56  // LDS row stride (elems) for 32-wide bf16 tiles: 112B = 16B-aligned, ~2-way bank conflict (free)

typedef __attribute__((ext_vector_type(8))) short short8;
typedef __attribute__((ext_vector_type(4))) float f32x4;
typedef unsigned short u16;

__device__ __forceinline__ u16 f2bf(float f) {
  union { float f; unsigned u; } v; v.f = f;
  unsigned r = v.u + 0x7fffu + ((v.u >> 16) & 1u);  // round-to-nearest-even
  return (u16)(r >> 16);
}

// ---------------- Kernel 1: QKV projections  y = x @ W^T  (NT GEMM, fp32 in, bf16 out) ----------------
__global__ __launch_bounds__(TB) void qkv_gemm(
    const float* __restrict__ query, const float* __restrict__ keys,
    const float* __restrict__ Wq, const float* __restrict__ Wk, const float* __restrict__ Wv,
    u16* __restrict__ Qb, u16* __restrict__ Kb, u16* __restrict__ Vb) {
  __shared__ u16 As[128 * LDST];
  __shared__ u16 Bs[128 * LDST];
  const int z = blockIdx.z;
  const float* __restrict__ x = (z == 0) ? query : keys;
  const float* __restrict__ W = (z == 0) ? Wq : (z == 1) ? Wk : Wv;
  u16* __restrict__ dst = (z == 0) ? Qb : (z == 1) ? Kb : Vb;

  const int t = threadIdx.x;
  const int lane = t & 63, wid = t >> 6;
  const int wr = wid >> 1, wc = wid & 1;
  const int fr = lane & 15, ko = (lane >> 4) * 8;
  const int m0 = blockIdx.x * 128, n0 = blockIdx.y * 128;

  f32x4 acc[4][4] = {};

  for (int k0 = 0; k0 < 1024; k0 += 32) {
#pragma unroll
    for (int it = 0; it < 4; ++it) {
      int j = it * 256 + t;
      int row = j >> 3, c4 = (j & 7) * 4;
      float4 va = *(const float4*)&x[(size_t)(m0 + row) * 1024 + k0 + c4];
      float4 vb = *(const float4*)&W[(size_t)(n0 + row) * 1024 + k0 + c4];
      *(ushort4*)&As[row * LDST + c4] = make_ushort4(f2bf(va.x), f2bf(va.y), f2bf(va.z), f2bf(va.w));
      *(ushort4*)&Bs[row * LDST + c4] = make_ushort4(f2bf(vb.x), f2bf(vb.y), f2bf(vb.z), f2bf(vb.w));
    }
    __syncthreads();
    short8 a[4], bfrag[4];
#pragma unroll
    for (int i = 0; i < 4; ++i) a[i] = *(const short8*)&As[(wr * 64 + i * 16 + fr) * LDST + ko];
#pragma unroll
    for (int j = 0; j < 4; ++j) bfrag[j] = *(const short8*)&Bs[(wc * 64 + j * 16 + fr) * LDST + ko];
#pragma unroll
    for (int i = 0; i < 4; ++i)
#pragma unroll
      for (int j = 0; j < 4; ++j)
        acc[i][j] = __builtin_amdgcn_mfma_f32_16x16x32_bf16(a[i], bfrag[j], acc[i][j], 0, 0, 0);
    __syncthreads();
  }

  const int h = blockIdx.y;
#pragma unroll
  for (int i = 0; i < 4; ++i)
#pragma unroll
    for (int j = 0; j < 4; ++j)
#pragma unroll
      for (int r = 0; r < 4; ++r) {
        int m = m0 + wr * 64 + i * 16 + (lane >> 4) * 4 + r;
        int d = wc * 64 + j * 16 + fr;
        int b_ = m >> 10, q = m & 1023;
        dst[(((size_t)(b_ * 8 + h)) * 1024 + q) * 128 + d] = f2bf(acc[i][j][r]);
      }
}

// ---------------- Kernel 2: V transpose  (b,h,k,d) -> (b,h,d,k) ----------------
__global__ __launch_bounds__(TB) void vtrans(const u16* __restrict__ Vb, u16* __restrict__ Vt) {
  __shared__ u16 tile[32][33];
  const int bh = blockIdx.z;
  const u16* __restrict__ src = Vb + (size_t)bh * 1024 * 128;
  u16* __restrict__ dst = Vt + (size_t)bh * 128 * 1024;
  const int k0 = blockIdx.x * 32, d0 = blockIdx.y * 32;
  const int t = threadIdx.x;
#pragma unroll
  for (int i = 0; i < 4; ++i) {
    int j = i * 256 + t;
    int r = j >> 5, c = j & 31;
    tile[r][c] = src[(size_t)(k0 + r) * 128 + d0 + c];
  }
  __syncthreads();
#pragma unroll
  for (int i = 0; i < 4; ++i) {
    int j = i * 256 + t;
    int r = j >> 5, c = j & 31;
    dst[(size_t)(d0 + r) * 1024 + k0 + c] = tile[c][r];
  }
}

// ---------------- Kernel 3: fused logits + softmax + PV ----------------
// Block = (qb: 32 q-rows, bh). 4 waves; wave w owns columns [w*256, w*256+256).
// S row (1024) held in registers: acc[2][16] f32x4 per lane.
__global__ __launch_bounds__(TB, 2) void fused_attn(
    const u16* __restrict__ Qb, const u16* __restrict__ Kb, const u16* __restrict__ Vt,
    const int* __restrict__ mask, const float* __restrict__ rel,
    float* __restrict__ sim, float* __restrict__ out) {
  __shared__ u16 Pl[32 * 1024];    // normalized P, bf16, XOR-swizzled
  __shared__ float redm[4][32];
  __shared__ float reds[4][32];

  const int qb = blockIdx.x;       // 32 q-blocks
  const int z = blockIdx.y;        // 64 bh
  const int h = z >> 3, b = z & 7;

  const int t = threadIdx.x;
  const int lane = t & 63, w = t >> 6;
  const int fr = lane & 15, g = lane >> 4;   // quarter-wave group
  const int ko = g * 8;

  const size_t bh_off = (size_t)(b * 8 + h) * 1024 * 128;
  const u16* __restrict__ Qp = Qb + bh_off + (size_t)(qb * 32) * 128;
  const u16* __restrict__ Kp = Kb + bh_off;
  const u16* __restrict__ Vp = Vt + bh_off;   // (d,k) layout

  // ---- Phase 1: S = Q.K^T  (rows 32, cols 1024; wave handles 256 cols) ----
  short8 qf[2][4];
#pragma unroll
  for (int m = 0; m < 2; ++m)
#pragma unroll
    for (int ks = 0; ks < 4; ++ks)
      qf[m][ks] = *(const short8*)&Qp[(size_t)(m * 16 + fr) * 128 + ks * 32 + ko];

  f32x4 acc[2][16] = {};
#pragma unroll
  for (int pt = 0; pt < 16; ++pt) {
    const u16* kb = Kp + (size_t)(w * 256 + pt * 16 + fr) * 128 + ko;
#pragma unroll
    for (int ks = 0; ks < 4; ++ks) {
      short8 kf = *(const short8*)&kb[ks * 32];
      acc[0][pt] = __builtin_amdgcn_mfma_f32_16x16x32_bf16(qf[0][ks], kf, acc[0][pt], 0, 0, 0);
      acc[1][pt] = __builtin_amdgcn_mfma_f32_16x16x32_bf16(qf[1][ks], kf, acc[1][pt], 0, 0, 0);
    }
  }

  // ---- Phase 2: rel + mask, in-register ----
  const float scale = 0.03125f;  // 1/sqrt(1024)
#pragma unroll
  for (int m = 0; m < 2; ++m)
#pragma unroll
    for (int r = 0; r < 4; ++r) {
      const int qrow = qb * 32 + m * 16 + g * 4 + r;
      const size_t rbase = ((size_t)b * 1024 + qrow) * 1024 + w * 256 + fr;
#pragma unroll
      for (int pt = 0; pt < 16; ++pt) {
        size_t idx = rbase + pt * 16;
        float v = (acc[m][pt][r] + rel[idx]) * scale;
        acc[m][pt][r] = (mask[idx] > 0) ? v : -1e9f;
      }
    }

  // ---- Phase 3: row max (local 16 -> shfl over 16-lane group -> LDS cross-wave) ----
  float mloc[2][4];
#pragma unroll
  for (int m = 0; m < 2; ++m)
#pragma unroll
    for (int r = 0; r < 4; ++r) {
      float mx = acc[m][0][r];
#pragma unroll
      for (int pt = 1; pt < 16; ++pt) mx = fmaxf(mx, acc[m][pt][r]);
      mx = fmaxf(mx, __shfl_xor(mx, 1));
      mx = fmaxf(mx, __shfl_xor(mx, 2));
      mx = fmaxf(mx, __shfl_xor(mx, 4));
      mx = fmaxf(mx, __shfl_xor(mx, 8));
      mloc[m][r] = mx;
    }
  if (fr == 0) {
#pragma unroll
    for (int m = 0; m < 2; ++m)
#pragma unroll
      for (int r = 0; r < 4; ++r) redm[w][m * 16 + g * 4 + r] = mloc[m][r];
  }
  __syncthreads();

  // ---- Phase 4: exp + row sum ----
  float inv[2][4];
#pragma unroll
  for (int m = 0; m < 2; ++m)
#pragma unroll
    for (int r = 0; r < 4; ++r) {
      const int rl = m * 16 + g * 4 + r;
      float mx = fmaxf(fmaxf(redm[0][rl], redm[1][rl]), fmaxf(redm[2][rl], redm[3][rl]));
      float s = 0.f;
#pragma unroll
      for (int pt = 0; pt < 16; ++pt) {
        float e = __expf(acc[m][pt][r] - mx);
        acc[m][pt][r] = e;
        s += e;
      }
      s += __shfl_xor(s, 1);
      s += __shfl_xor(s, 2);
      s += __shfl_xor(s, 4);
      s += __shfl_xor(s, 8);
      inv[m][r] = s;  // stash sum; finish after cross-wave reduce
    }
  if (fr == 0) {
#pragma unroll
    for (int m = 0; m < 2; ++m)
#pragma unroll
      for (int r = 0; r < 4; ++r) reds[w][m * 16 + g * 4 + r] = inv[m][r];
  }
  __syncthreads();

  // ---- Phase 5: normalize; write sim (fp32, global) + P (bf16, swizzled LDS) ----
  const size_t sim_base = ((size_t)(h * 8 + b) * 1024 + qb * 32) * 1024;
#pragma unroll
  for (int m = 0; m < 2; ++m)
#pragma unroll
    for (int r = 0; r < 4; ++r) {
      const int rl = m * 16 + g * 4 + r;
      float s = reds[0][rl] + reds[1][rl] + reds[2][rl] + reds[3][rl];
      float iv = 1.0f / s;
      const int swz = (rl & 15) << 3;  // element XOR (byte<<4)
#pragma unroll
      for (int pt = 0; pt < 16; ++pt) {
        const int col = w * 256 + pt * 16 + fr;
        float p = acc[m][pt][r] * iv;
        sim[sim_base + (size_t)rl * 1024 + col] = p;
        Pl[rl * 1024 + (col ^ swz)] = f2bf(p);
      }
    }
  __syncthreads();

  // ---- Phase 6: out(32x128) = P(32x1024) @ V^T  (Vt is (d,k), k-contiguous) ----
  // wave w -> d-tiles {2w, 2w+1}, m-tiles {0,1}
  f32x4 oacc[2][2] = {};
  const int d0 = w * 32;
#pragma unroll
  for (int ks = 0; ks < 32; ++ks) {
    short8 pa[2], vb2[2];
#pragma unroll
    for (int m = 0; m < 2; ++m) {
      const int prow = m * 16 + fr;
      pa[m] = *(const short8*)&Pl[prow * 1024 + ((ks * 32 + ko) ^ ((prow & 15) << 3))];
    }
#pragma unroll
    for (int dt = 0; dt < 2; ++dt)
      vb2[dt] = *(const short8*)&Vp[(size_t)(d0 + dt * 16 + fr) * 1024 + ks * 32 + ko];
#pragma unroll
    for (int m = 0; m < 2; ++m)
#pragma unroll
      for (int dt = 0; dt < 2; ++dt)
        oacc[m][dt] = __builtin_amdgcn_mfma_f32_16x16x32_bf16(pa[m], vb2[dt], oacc[m][dt], 0, 0, 0);
  }

#pragma unroll
  for (int m = 0; m < 2; ++m)
#pragma unroll
    for (int dt = 0; dt < 2; ++dt)
#pragma unroll
      for (int r = 0; r < 4; ++r) {
        const int q = qb * 32 + m * 16 + g * 4 + r;
        const int d = d0 + dt * 16 + fr;
        out[((size_t)b * 1024 + q) * 1024 + h * 128 + d] = oacc[m][dt][r];
      }
}

extern "C" void kernel_launch(void* const* d_in, const int* in_sizes, int n_in,
                              void* d_out, int out_size, void* d_ws, size_t ws_size,
                              hipStream_t stream) {
  (void)in_sizes; (void)n_in; (void)out_size; (void)ws_size;
  const float* query = (const float*)d_in[0];
  const float* keys  = (const float*)d_in[1];
  const int*   mask  = (const int*)d_in[2];
  const float* rel   = (const float*)d_in[3];
  const float* Wq    = (const float*)d_in[4];
  const float* Wk    = (const float*)d_in[5];
  const float* Wv    = (const float*)d_in[6];

  float* out = (float*)d_out;                       // (B,Lq,D) = 8M floats
  float* sim = out + (size_t)8 * 1024 * 1024;       // (H*B,Lq,Lk) = 64M floats

  const size_t NE = (size_t)8 * 8 * 1024 * 128;     // 8.39M bf16 elems per buffer
  u16* Qb = (u16*)d_ws;                             // ws usage: 64 MB total
  u16* Kb = Qb + NE;
  u16* Vb = Kb + NE;
  u16* Vt = Vb + NE;

  qkv_gemm<<<dim3(64, 8, 3), TB, 0, stream>>>(query, keys, Wq, Wk, Wv, Qb, Kb, Vb);
  vtrans<<<dim3(32, 4, 64), TB, 0, stream>>>(Vb, Vt);
  fused_attn<<<dim3(32, 64), TB, 0, stream>>>(Qb, Kb, Vt, mask, rel, sim, out);
}